// Round 12
// baseline (73.812 us; speedup 1.0000x reference)
//
#include <hip/hip_runtime.h>
#include <stdint.h>

#define AS1 __attribute__((address_space(1)))
#define AS3 __attribute__((address_space(3)))

typedef __attribute__((ext_vector_type(2))) float f32x2;
typedef __attribute__((ext_vector_type(4))) float f32x4;
typedef __attribute__((ext_vector_type(8))) short bf16x8;

static constexpr int N_ = 4, C_ = 256, HW_ = 4096;
static constexpr int CO_ = 256, KTAP = 9;
static constexpr int NSTEP = 72;                     // K-steps of 32
static constexpr int A_PLANE = 16 * 64 * 16;         // one BK=32 plane of A: 16KB
static constexpr size_t ROW_BYTES = (size_t)NSTEP * 4096;  // 288KB per output row

static constexpr size_t NHWC_BYTES = (size_t)N_ * HW_ * C_ * 2;   // 8 MB
static constexpr size_t ABF_OFF    = NHWC_BYTES;
static constexpr size_t ABF_BYTES  = (size_t)NSTEP * A_PLANE;     // 1.18 MB
static constexpr size_t BG_OFF     = ABF_OFF + ABF_BYTES;
static constexpr size_t BG_BYTES   = (size_t)256 * ROW_BYTES;     // 75.5 MB

__device__ inline unsigned f2bf(float f) {
  unsigned u = __builtin_bit_cast(unsigned, f);
  unsigned r = u + 0x7FFFu + ((u >> 16) & 1u);
  return r >> 16;
}
__device__ inline float asf(unsigned u) { return __builtin_bit_cast(float, u); }

// ---------------- merged prep: NCHW->NHWC bf16 + filter->fragment-major ------
__global__ __launch_bounds__(256) void k_prep(const float* __restrict__ in,
                                              const float* __restrict__ filt,
                                              unsigned short* __restrict__ nhwc,
                                              unsigned short* __restrict__ abf2) {
  int b = blockIdx.x;
  int t = threadIdx.x;
  if (b < 1024) {
    __shared__ float tile[64][65];
    int n = b >> 8, cg = (b >> 6) & 3, hwg = b & 63;
    int c0 = cg * 64, hw0 = hwg * 64;
    int col = t & 63, r0 = t >> 6;
#pragma unroll
    for (int i = 0; i < 16; ++i) {
      int row = r0 + i * 4;
      tile[row][col] = in[(size_t)(n * C_ + c0 + row) * HW_ + hw0 + col];
    }
    __syncthreads();
    int pr = t >> 2, cc0 = (t & 3) * 16;
    unsigned us[8];
#pragma unroll
    for (int i = 0; i < 8; ++i) {
      unsigned lo = f2bf(tile[cc0 + 2 * i][pr]);
      unsigned hi = f2bf(tile[cc0 + 2 * i + 1][pr]);
      us[i] = lo | (hi << 16);
    }
    unsigned* dst = (unsigned*)(nhwc + (size_t)(n * HW_ + hw0 + pr) * C_ + c0 + cc0);
    ((uint4*)dst)[0] = make_uint4(us[0], us[1], us[2], us[3]);
    ((uint4*)dst)[1] = make_uint4(us[4], us[5], us[6], us[7]);
  } else {
    // abf2[((s*16 + rb)*64 + lane)*8 + j]: s = tap*8+(c>>5), rb=o>>4,
    // lane = ((c>>3)&3)*16 + (o&15), j = c&7.
    int gid = (b - 1024) * 256 + t;
    int o = gid >> 8, c = gid & 255;
    const float* f = filt + (size_t)(o * C_ + c) * KTAP;
    int rb = o >> 4;
    int lane = ((c >> 3) & 3) * 16 + (o & 15);
    int j = c & 7;
#pragma unroll
    for (int tap = 0; tap < KTAP; ++tap) {
      int s = tap * 8 + (c >> 5);
      abf2[((size_t)(s * 16 + rb) * 64 + lane) * 8 + j] = (unsigned short)f2bf(f[tap]);
    }
  }
}

__device__ __forceinline__ f32x2 unpk(unsigned u) {
  return (f32x2){asf(u << 16), asf(u & 0xffff0000u)};
}

// bilinear combine: 8 channels (one uint4 per corner) -> 16B (8 bf16)
__device__ __forceinline__ uint4 comb8(const uint4& g0, const uint4& g1,
                                       const uint4& g2, const uint4& g3, f32x4 w) {
  f32x2 r0 = w.x * unpk(g0.x) + w.y * unpk(g1.x) + w.z * unpk(g2.x) + w.w * unpk(g3.x);
  f32x2 r1 = w.x * unpk(g0.y) + w.y * unpk(g1.y) + w.z * unpk(g2.y) + w.w * unpk(g3.y);
  f32x2 r2 = w.x * unpk(g0.z) + w.y * unpk(g1.z) + w.z * unpk(g2.z) + w.w * unpk(g3.z);
  f32x2 r3 = w.x * unpk(g0.w) + w.y * unpk(g1.w) + w.z * unpk(g2.w) + w.w * unpk(g3.w);
  unsigned o0, o1, o2, o3;
  asm("v_cvt_pk_bf16_f32 %0, %1, %2" : "=v"(o0) : "v"(r0.x), "v"(r0.y));
  asm("v_cvt_pk_bf16_f32 %0, %1, %2" : "=v"(o1) : "v"(r1.x), "v"(r1.y));
  asm("v_cvt_pk_bf16_f32 %0, %1, %2" : "=v"(o2) : "v"(r2.x), "v"(r2.y));
  asm("v_cvt_pk_bf16_f32 %0, %1, %2" : "=v"(o3) : "v"(r3.x), "v"(r3.y));
  return make_uint4(o0, o1, o2, o3);
}

#define MFMA_BF16 __builtin_amdgcn_mfma_f32_16x16x32_bf16

// ---------------- fused row kernel: sample own row -> ws -> stream GEMM ------
// 256 blocks (one per output row) x 512 threads (8 waves).
// Phase 1: thread (px=t>>3, cq=t&7) builds B tiles for all 9 taps into
//   bgrow + s*4096, tile layout [kq=ch>>3 mod4][px][16B] (bank-clean).
// Phase 2: 8 homogeneous waves (wave tile 32 Cout x 64 px); B staged via
//   global_load_lds into a 4-buffer ring (depth-2), raw s_barrier + vmcnt(1)
//   counted waits (never drains the in-flight prefetch).
__global__ __launch_bounds__(512, 2) void k_dcn(const unsigned short* __restrict__ nhwc,
                                                const unsigned short* __restrict__ abf2,
                                                const float* __restrict__ offs,
                                                const float* __restrict__ msk,
                                                unsigned short* __restrict__ bglob,
                                                float* __restrict__ out) {
  __shared__ __align__(16) unsigned short Bl[4][2048];  // 4 x 4KB ring
  __shared__ float recW[KTAP * 64 * 4];
  __shared__ unsigned recA[KTAP * 64 * 4];

  int bid = blockIdx.x;
  int b = ((bid & 7) << 5) | (bid >> 3);  // XCD-aware swizzle (bijective)
  int n = b >> 6;
  int ho = b & 63;
  int hw0 = ho << 6;
  int t = threadIdx.x;

  // --- records for all 576 (px, tap) pairs ---
  for (int r = t; r < 576; r += 512) {
    int pl = r / 9;
    int tap = r - pl * 9;
    int hw = hw0 + pl;
    float dy = offs[(size_t)(n * 18 + 2 * tap) * HW_ + hw];
    float dx = offs[(size_t)(n * 18 + 2 * tap + 1) * HW_ + hw];
    float mk = msk[(size_t)(n * 9 + tap) * HW_ + hw];
    float y = (float)(ho - 1 + tap / 3) + dy;
    float x = (float)(pl - 1 + tap % 3) + dx;
    float fy = floorf(y), fx = floorf(x);
    float ly = y - fy, lx = x - fx;
    int y0 = (int)fy, x0 = (int)fx;
    int y1 = y0 + 1, x1 = x0 + 1;
    float vy0 = (y0 >= 0 && y0 < 64) ? 1.f : 0.f;
    float vy1 = (y1 >= 0 && y1 < 64) ? 1.f : 0.f;
    float vx0 = (x0 >= 0 && x0 < 64) ? 1.f : 0.f;
    float vx1 = (x1 >= 0 && x1 < 64) ? 1.f : 0.f;
    int y0c = min(max(y0, 0), 63), y1c = min(max(y1, 0), 63);
    int x0c = min(max(x0, 0), 63), x1c = min(max(x1, 0), 63);
    int base = (tap * 64 + pl) * 4;
    recW[base + 0] = (1.f - ly) * (1.f - lx) * mk * vy0 * vx0;
    recW[base + 1] = (1.f - ly) * lx * mk * vy0 * vx1;
    recW[base + 2] = ly * (1.f - lx) * mk * vy1 * vx0;
    recW[base + 3] = ly * lx * mk * vy1 * vx1;
    recA[base + 0] = (unsigned)((y0c * 64 + x0c) * 512);
    recA[base + 1] = (unsigned)((y0c * 64 + x1c) * 512);
    recA[base + 2] = (unsigned)((y1c * 64 + x0c) * 512);
    recA[base + 3] = (unsigned)((y1c * 64 + x1c) * 512);
  }
  __syncthreads();

  // ================= phase 1: sample this row into ws =================
  {
    int px = t >> 3, cq = t & 7;
    unsigned c16 = (unsigned)(cq * 16);
    const char* nb = (const char*)nhwc + (size_t)n * HW_ * C_ * 2;
    char* bgrow = (char*)bglob + (size_t)b * ROW_BYTES;
    char* outb = bgrow + (cq & 3) * 1024 + px * 16;
    for (int tap = 0; tap < KTAP; ++tap) {
      f32x4 w = *(const f32x4*)&recW[(tap * 64 + px) * 4];
      uint4 ra = *(const uint4*)&recA[(tap * 64 + px) * 4];
      uint4 g0[4], g1[4], g2[4], g3[4];
#pragma unroll
      for (int j = 0; j < 4; ++j) {
        unsigned o_ = (unsigned)(j * 128) + c16;
        g0[j] = *(const uint4*)(nb + ra.x + o_);
        g1[j] = *(const uint4*)(nb + ra.y + o_);
        g2[j] = *(const uint4*)(nb + ra.z + o_);
        g3[j] = *(const uint4*)(nb + ra.w + o_);
      }
      int sbase = tap * 8 + (cq >> 2);
#pragma unroll
      for (int j = 0; j < 4; ++j) {
        uint4 o4 = comb8(g0[j], g1[j], g2[j], g3[j], w);
        *(uint4*)(outb + (size_t)(sbase + j * 2) * 4096) = o4;
      }
    }
  }
  __syncthreads();  // drains phase-1 stores (vmcnt 0)

  // ================= phase 2: streaming GEMM over own row =================
  int lane = t & 63, wv = t >> 6;
  const char* bgrow = (const char*)bglob + (size_t)b * ROW_BYTES;
  const char* aoff = (const char*)abf2 + ((wv * 2) * 64 + lane) * 16;
  int kq = lane >> 4, pxl = lane & 15;
  const int bo0 = kq * 1024 + (0 * 16 + pxl) * 16;
  const int bo1 = kq * 1024 + (1 * 16 + pxl) * 16;
  const int bo2 = kq * 1024 + (2 * 16 + pxl) * 16;
  const int bo3 = kq * 1024 + (3 * 16 + pxl) * 16;

  f32x4 acc[2][4];
#pragma unroll
  for (int mi = 0; mi < 2; ++mi)
#pragma unroll
    for (int ni = 0; ni < 4; ++ni) acc[mi][ni] = (f32x4){0.f, 0.f, 0.f, 0.f};

  bf16x8 afc0, afc1, afn0, afn1;

  // prologue: stage B(0)->buf0, B(1)->buf1; load A(0); wait both tiles.
  if (wv < 4) {
    __builtin_amdgcn_global_load_lds(
        (const AS1 void*)(bgrow + wv * 1024 + lane * 16),
        (AS3 void*)((char*)&Bl[0][0] + wv * 1024 + lane * 16), 16, 0, 0);
    __builtin_amdgcn_global_load_lds(
        (const AS1 void*)(bgrow + 4096 + wv * 1024 + lane * 16),
        (AS3 void*)((char*)&Bl[0][0] + 4096 + wv * 1024 + lane * 16), 16, 0, 0);
  }
  afc0 = *(const bf16x8*)(aoff);
  afc1 = *(const bf16x8*)(aoff + 1024);
  asm volatile("s_waitcnt vmcnt(2)" ::: "memory");  // both gloads retired
  __builtin_amdgcn_sched_barrier(0);
  __builtin_amdgcn_s_barrier();
  asm volatile("" ::: "memory");

  for (int s = 0; s < NSTEP; ++s) {
    int s1 = s + 1 < NSTEP ? s + 1 : NSTEP - 1;
    // A(s+1) prefetch (issued BEFORE this step's gload -> vmcnt order fixed)
    afn0 = *(const bf16x8*)(aoff + (size_t)s1 * A_PLANE);
    afn1 = *(const bf16x8*)(aoff + (size_t)s1 * A_PLANE + 1024);
    __builtin_amdgcn_sched_barrier(0);
    if (s < NSTEP - 2 && wv < 4) {
      int s2 = s + 2;
      __builtin_amdgcn_global_load_lds(
          (const AS1 void*)(bgrow + (size_t)s2 * 4096 + wv * 1024 + lane * 16),
          (AS3 void*)((char*)&Bl[0][0] + (s2 & 3) * 4096 + wv * 1024 + lane * 16),
          16, 0, 0);
    }
    {
      const char* bb = (const char*)&Bl[0][0] + (s & 3) * 4096;
      bf16x8 b0 = *(const bf16x8*)(bb + bo0);
      bf16x8 b1 = *(const bf16x8*)(bb + bo1);
      bf16x8 b2 = *(const bf16x8*)(bb + bo2);
      bf16x8 b3 = *(const bf16x8*)(bb + bo3);
      __builtin_amdgcn_s_setprio(1);
      acc[0][0] = MFMA_BF16(afc0, b0, acc[0][0], 0, 0, 0);
      acc[1][0] = MFMA_BF16(afc1, b0, acc[1][0], 0, 0, 0);
      acc[0][1] = MFMA_BF16(afc0, b1, acc[0][1], 0, 0, 0);
      acc[1][1] = MFMA_BF16(afc1, b1, acc[1][1], 0, 0, 0);
      acc[0][2] = MFMA_BF16(afc0, b2, acc[0][2], 0, 0, 0);
      acc[1][2] = MFMA_BF16(afc1, b2, acc[1][2], 0, 0, 0);
      acc[0][3] = MFMA_BF16(afc0, b3, acc[0][3], 0, 0, 0);
      acc[1][3] = MFMA_BF16(afc1, b3, acc[1][3], 0, 0, 0);
      __builtin_amdgcn_s_setprio(0);
    }
    // retire gload(s+1) (and A(s+1)); keep gload(s+2) in flight
    asm volatile("s_waitcnt vmcnt(1)" ::: "memory");
    __builtin_amdgcn_sched_barrier(0);
    __builtin_amdgcn_s_barrier();
    asm volatile("" ::: "memory");
    afc0 = afn0;
    afc1 = afn1;
  }

  // epilogue: D col=lane&15 (px), row=(lane>>4)*4+jj (Cout)
  float* ob = out + (size_t)n * CO_ * HW_ + hw0;
#pragma unroll
  for (int mi = 0; mi < 2; ++mi)
#pragma unroll
    for (int ni = 0; ni < 4; ++ni)
#pragma unroll
      for (int jj = 0; jj < 4; ++jj) {
        int o = wv * 32 + mi * 16 + (lane >> 4) * 4 + jj;
        int hw = ni * 16 + (lane & 15);
        ob[(size_t)o * HW_ + hw] = acc[mi][ni][jj];
      }
}

extern "C" void kernel_launch(void* const* d_in, const int* in_sizes, int n_in,
                              void* d_out, int out_size, void* d_ws, size_t ws_size,
                              hipStream_t stream) {
  const float* inp  = (const float*)d_in[0];
  const float* filt = (const float*)d_in[1];
  const float* offs = (const float*)d_in[2];
  const float* msk  = (const float*)d_in[3];
  float* out = (float*)d_out;
  if (ws_size < BG_OFF + BG_BYTES) return;  // ~85 MB scratch (verified available)
  unsigned short* nhwc  = (unsigned short*)d_ws;
  unsigned short* abf2  = (unsigned short*)((char*)d_ws + ABF_OFF);
  unsigned short* bglob = (unsigned short*)((char*)d_ws + BG_OFF);

  k_prep<<<1280, 256, 0, stream>>>(inp, filt, nhwc, abf2);
  k_dcn<<<256, 512, 0, stream>>>(nhwc, abf2, offs, msk, bglob, out);
}

// Round 13
// 49.590 us; speedup vs baseline: 1.4884x; 1.4884x over previous
//
#include <hip/hip_runtime.h>
#include <stdint.h>

typedef __attribute__((ext_vector_type(2))) float f32x2;
typedef __attribute__((ext_vector_type(4))) float f32x4;
typedef __attribute__((ext_vector_type(8))) short bf16x8;

static constexpr int N_ = 4, C_ = 256, HW_ = 4096;
static constexpr int CO_ = 256, KTAP = 9;
static constexpr int NSTEP = 72;                 // K-steps of 32
static constexpr int A_PLANE = 16 * 64 * 16;     // one BK=32 plane of A: 16KB

static constexpr size_t NHWC_BYTES = (size_t)N_ * HW_ * C_ * 2;  // 8 MB
static constexpr size_t ABF_OFF    = NHWC_BYTES;
static constexpr size_t ABF_BYTES  = (size_t)NSTEP * A_PLANE;    // 1.18 MB

__device__ inline unsigned f2bf(float f) {
  unsigned u = __builtin_bit_cast(unsigned, f);
  unsigned r = u + 0x7FFFu + ((u >> 16) & 1u);
  return r >> 16;
}
__device__ inline float asf(unsigned u) { return __builtin_bit_cast(float, u); }

// ---------------- merged prep: NCHW->NHWC bf16 + filter->fragment-major ------
__global__ __launch_bounds__(256) void k_prep(const float* __restrict__ in,
                                              const float* __restrict__ filt,
                                              unsigned short* __restrict__ nhwc,
                                              unsigned short* __restrict__ abf2) {
  int b = blockIdx.x;
  int t = threadIdx.x;
  if (b < 1024) {
    __shared__ float tile[64][65];
    int n = b >> 8, cg = (b >> 6) & 3, hwg = b & 63;
    int c0 = cg * 64, hw0 = hwg * 64;
    int col = t & 63, r0 = t >> 6;
#pragma unroll
    for (int i = 0; i < 16; ++i) {
      int row = r0 + i * 4;
      tile[row][col] = in[(size_t)(n * C_ + c0 + row) * HW_ + hw0 + col];
    }
    __syncthreads();
    int pr = t >> 2, cc0 = (t & 3) * 16;
    unsigned us[8];
#pragma unroll
    for (int i = 0; i < 8; ++i) {
      unsigned lo = f2bf(tile[cc0 + 2 * i][pr]);
      unsigned hi = f2bf(tile[cc0 + 2 * i + 1][pr]);
      us[i] = lo | (hi << 16);
    }
    unsigned* dst = (unsigned*)(nhwc + (size_t)(n * HW_ + hw0 + pr) * C_ + c0 + cc0);
    ((uint4*)dst)[0] = make_uint4(us[0], us[1], us[2], us[3]);
    ((uint4*)dst)[1] = make_uint4(us[4], us[5], us[6], us[7]);
  } else {
    // abf2[((s*16 + rb)*64 + lane)*8 + j]: s = tap*8+(c>>5), rb=o>>4,
    // lane = ((c>>3)&3)*16 + (o&15), j = c&7.
    int gid = (b - 1024) * 256 + t;
    int o = gid >> 8, c = gid & 255;
    const float* f = filt + (size_t)(o * C_ + c) * KTAP;
    int rb = o >> 4;
    int lane = ((c >> 3) & 3) * 16 + (o & 15);
    int j = c & 7;
#pragma unroll
    for (int tap = 0; tap < KTAP; ++tap) {
      int s = tap * 8 + (c >> 5);
      abf2[((size_t)(s * 16 + rb) * 64 + lane) * 8 + j] = (unsigned short)f2bf(f[tap]);
    }
  }
}

__device__ __forceinline__ f32x2 unpk(unsigned u) {
  return (f32x2){asf(u << 16), asf(u & 0xffff0000u)};
}

// bilinear combine: 8 channels (one uint4 per corner) -> 16B (8 bf16)
__device__ __forceinline__ uint4 comb8(const uint4& g0, const uint4& g1,
                                       const uint4& g2, const uint4& g3, f32x4 w) {
  f32x2 r0 = w.x * unpk(g0.x) + w.y * unpk(g1.x) + w.z * unpk(g2.x) + w.w * unpk(g3.x);
  f32x2 r1 = w.x * unpk(g0.y) + w.y * unpk(g1.y) + w.z * unpk(g2.y) + w.w * unpk(g3.y);
  f32x2 r2 = w.x * unpk(g0.z) + w.y * unpk(g1.z) + w.z * unpk(g2.z) + w.w * unpk(g3.z);
  f32x2 r3 = w.x * unpk(g0.w) + w.y * unpk(g1.w) + w.z * unpk(g2.w) + w.w * unpk(g3.w);
  unsigned o0, o1, o2, o3;
  asm("v_cvt_pk_bf16_f32 %0, %1, %2" : "=v"(o0) : "v"(r0.x), "v"(r0.y));
  asm("v_cvt_pk_bf16_f32 %0, %1, %2" : "=v"(o1) : "v"(r1.x), "v"(r1.y));
  asm("v_cvt_pk_bf16_f32 %0, %1, %2" : "=v"(o2) : "v"(r2.x), "v"(r2.y));
  asm("v_cvt_pk_bf16_f32 %0, %1, %2" : "=v"(o3) : "v"(r3.x), "v"(r3.y));
  return make_uint4(o0, o1, o2, o3);
}

#define MFMA_BF16 __builtin_amdgcn_mfma_f32_16x16x32_bf16

// ---------------- fused tap-grain kernel: sample tap -> LDS -> GEMM ----------
// 256 blocks (one per output row) x 512 threads (8 homogeneous waves).
// LDS: 2 tap-buffers x 32KB (8 steps x 4KB). Per step: plane kq=ch>>3 (0..3):
//   addr = kq*1024 + px*16 (bank-minimal for b128 read AND write).
// Phase(tap): issue 16 gathers for tap+1 -> 8 barrier-free GEMM steps from
// buf[tap&1] -> comb+ds_write tap+1 into buf[(tap+1)&1] -> lgkm drain -> bar.
__global__ __launch_bounds__(512, 2) void k_dcn(const unsigned short* __restrict__ nhwc,
                                                const unsigned short* __restrict__ abf2,
                                                const float* __restrict__ offs,
                                                const float* __restrict__ msk,
                                                float* __restrict__ out) {
  __shared__ __align__(16) unsigned short Bl[2][16384];  // 2 x 32KB tap buffers
  __shared__ float recW[KTAP * 64 * 4];
  __shared__ unsigned recA[KTAP * 64 * 4];

  int bid = blockIdx.x;
  int b = ((bid & 7) << 5) | (bid >> 3);  // XCD-aware swizzle (bijective, 256%8==0)
  int n = b >> 6;
  int ho = b & 63;
  int hw0 = ho << 6;
  int t = threadIdx.x;

  // --- records for all 576 (px, tap) pairs ---
  for (int r = t; r < 576; r += 512) {
    int pl = r / 9;
    int tap = r - pl * 9;
    int hw = hw0 + pl;
    float dy = offs[(size_t)(n * 18 + 2 * tap) * HW_ + hw];
    float dx = offs[(size_t)(n * 18 + 2 * tap + 1) * HW_ + hw];
    float mk = msk[(size_t)(n * 9 + tap) * HW_ + hw];
    float y = (float)(ho - 1 + tap / 3) + dy;
    float x = (float)(pl - 1 + tap % 3) + dx;
    float fy = floorf(y), fx = floorf(x);
    float ly = y - fy, lx = x - fx;
    int y0 = (int)fy, x0 = (int)fx;
    int y1 = y0 + 1, x1 = x0 + 1;
    float vy0 = (y0 >= 0 && y0 < 64) ? 1.f : 0.f;
    float vy1 = (y1 >= 0 && y1 < 64) ? 1.f : 0.f;
    float vx0 = (x0 >= 0 && x0 < 64) ? 1.f : 0.f;
    float vx1 = (x1 >= 0 && x1 < 64) ? 1.f : 0.f;
    int y0c = min(max(y0, 0), 63), y1c = min(max(y1, 0), 63);
    int x0c = min(max(x0, 0), 63), x1c = min(max(x1, 0), 63);
    int base = (tap * 64 + pl) * 4;
    recW[base + 0] = (1.f - ly) * (1.f - lx) * mk * vy0 * vx0;
    recW[base + 1] = (1.f - ly) * lx * mk * vy0 * vx1;
    recW[base + 2] = ly * (1.f - lx) * mk * vy1 * vx0;
    recW[base + 3] = ly * lx * mk * vy1 * vx1;
    recA[base + 0] = (unsigned)((y0c * 64 + x0c) * 512);
    recA[base + 1] = (unsigned)((y0c * 64 + x1c) * 512);
    recA[base + 2] = (unsigned)((y1c * 64 + x0c) * 512);
    recA[base + 3] = (unsigned)((y1c * 64 + x1c) * 512);
  }
  __syncthreads();

  int lane = t & 63, wv = t >> 6;
  // sampler ids: thread = (px 0..63, cq 0..7); chunk j: channels j*64+cq*8..+8
  // -> step sj = j*2 + (cq>>2), plane (cq&3), byte px*16.
  int px = t >> 3, cq = t & 7;
  unsigned cq16 = (unsigned)(cq * 16);
  const char* nb = (const char*)nhwc + (size_t)n * HW_ * C_ * 2;
  const int wchunk = (cq & 3) * 1024 + px * 16;          // within-step byte
  const int sj0 = (cq >> 2) * 4096;                       // step base for j=0

  // consumer ids: wave wv owns Cout [wv*32, wv*32+32)
  const char* aoff = (const char*)abf2 + ((wv * 2) * 64 + lane) * 16;
  int kq = lane >> 4, pxl = lane & 15;
  const int bo0 = kq * 1024 + (0 * 16 + pxl) * 16;
  const int bo1 = kq * 1024 + (1 * 16 + pxl) * 16;
  const int bo2 = kq * 1024 + (2 * 16 + pxl) * 16;
  const int bo3 = kq * 1024 + (3 * 16 + pxl) * 16;

  f32x4 acc[2][4];
#pragma unroll
  for (int mi = 0; mi < 2; ++mi)
#pragma unroll
    for (int ni = 0; ni < 4; ++ni) acc[mi][ni] = (f32x4){0.f, 0.f, 0.f, 0.f};

  bf16x8 afc0, afc1, afn0, afn1;

  // ---- prologue: sample tap 0 into buf0; load A(0) ----
  {
    f32x4 w0 = *(const f32x4*)&recW[px * 4];
    uint4 ra = *(const uint4*)&recA[px * 4];
    uint4 g0[4], g1[4], g2[4], g3[4];
#pragma unroll
    for (int j = 0; j < 4; ++j) {
      unsigned o_ = (unsigned)(j * 128) + cq16;
      g0[j] = *(const uint4*)(nb + ra.x + o_);
      g1[j] = *(const uint4*)(nb + ra.y + o_);
      g2[j] = *(const uint4*)(nb + ra.z + o_);
      g3[j] = *(const uint4*)(nb + ra.w + o_);
    }
    char* wb = (char*)&Bl[0][0] + sj0 + wchunk;
#pragma unroll
    for (int j = 0; j < 4; ++j)
      *(uint4*)(wb + j * 8192) = comb8(g0[j], g1[j], g2[j], g3[j], w0);
  }
  afc0 = *(const bf16x8*)(aoff);
  afc1 = *(const bf16x8*)(aoff + 1024);
  __syncthreads();

  // ---- main loop: 9 tap-phases ----
  for (int tap = 0; tap < KTAP; ++tap) {
    const int rd = (tap & 1) << 15;      // byte offset of read buffer (32KB)
    const int wr = rd ^ (1 << 15);

    // 1. issue gathers for tap+1 (consumed ~2000cy later)
    uint4 g0[4], g1[4], g2[4], g3[4];
    f32x4 wN;
    if (tap < KTAP - 1) {
      wN = *(const f32x4*)&recW[((tap + 1) * 64 + px) * 4];
      uint4 ra = *(const uint4*)&recA[((tap + 1) * 64 + px) * 4];
#pragma unroll
      for (int j = 0; j < 4; ++j) {
        unsigned o_ = (unsigned)(j * 128) + cq16;
        g0[j] = *(const uint4*)(nb + ra.x + o_);
        g1[j] = *(const uint4*)(nb + ra.y + o_);
        g2[j] = *(const uint4*)(nb + ra.z + o_);
        g3[j] = *(const uint4*)(nb + ra.w + o_);
      }
    }
    __builtin_amdgcn_sched_barrier(0);

    // 2. 8 barrier-free GEMM steps (compiler pipelines ds_read -> MFMA)
#pragma unroll
    for (int s8 = 0; s8 < 8; ++s8) {
      int gs1 = tap * 8 + s8 + 1;
      if (gs1 >= NSTEP) gs1 = NSTEP - 1;
      afn0 = *(const bf16x8*)(aoff + (size_t)gs1 * A_PLANE);
      afn1 = *(const bf16x8*)(aoff + (size_t)gs1 * A_PLANE + 1024);
      const char* bb = (const char*)&Bl[0][0] + rd + s8 * 4096;
      bf16x8 b0 = *(const bf16x8*)(bb + bo0);
      bf16x8 b1 = *(const bf16x8*)(bb + bo1);
      bf16x8 b2 = *(const bf16x8*)(bb + bo2);
      bf16x8 b3 = *(const bf16x8*)(bb + bo3);
      __builtin_amdgcn_s_setprio(1);
      acc[0][0] = MFMA_BF16(afc0, b0, acc[0][0], 0, 0, 0);
      acc[1][0] = MFMA_BF16(afc1, b0, acc[1][0], 0, 0, 0);
      acc[0][1] = MFMA_BF16(afc0, b1, acc[0][1], 0, 0, 0);
      acc[1][1] = MFMA_BF16(afc1, b1, acc[1][1], 0, 0, 0);
      acc[0][2] = MFMA_BF16(afc0, b2, acc[0][2], 0, 0, 0);
      acc[1][2] = MFMA_BF16(afc1, b2, acc[1][2], 0, 0, 0);
      acc[0][3] = MFMA_BF16(afc0, b3, acc[0][3], 0, 0, 0);
      acc[1][3] = MFMA_BF16(afc1, b3, acc[1][3], 0, 0, 0);
      __builtin_amdgcn_s_setprio(0);
      afc0 = afn0;
      afc1 = afn1;
    }

    // 3. combine + write tap+1 into buf[wr]; drain LDS writes; barrier
    if (tap < KTAP - 1) {
      char* wb = (char*)&Bl[0][0] + wr + sj0 + wchunk;
#pragma unroll
      for (int j = 0; j < 4; ++j)
        *(uint4*)(wb + j * 8192) = comb8(g0[j], g1[j], g2[j], g3[j], wN);
      asm volatile("s_waitcnt lgkmcnt(0)" ::: "memory");
    }
    __builtin_amdgcn_sched_barrier(0);
    __builtin_amdgcn_s_barrier();
    asm volatile("" ::: "memory");
  }

  // ---- epilogue: D col=lane&15 (px), row=(lane>>4)*4+jj (Cout) ----
  float* ob = out + (size_t)n * CO_ * HW_ + hw0;
#pragma unroll
  for (int mi = 0; mi < 2; ++mi)
#pragma unroll
    for (int ni = 0; ni < 4; ++ni)
#pragma unroll
      for (int jj = 0; jj < 4; ++jj) {
        int o = wv * 32 + mi * 16 + (lane >> 4) * 4 + jj;
        int hw = ni * 16 + (lane & 15);
        ob[(size_t)o * HW_ + hw] = acc[mi][ni][jj];
      }
}

extern "C" void kernel_launch(void* const* d_in, const int* in_sizes, int n_in,
                              void* d_out, int out_size, void* d_ws, size_t ws_size,
                              hipStream_t stream) {
  const float* inp  = (const float*)d_in[0];
  const float* filt = (const float*)d_in[1];
  const float* offs = (const float*)d_in[2];
  const float* msk  = (const float*)d_in[3];
  float* out = (float*)d_out;
  if (ws_size < ABF_OFF + ABF_BYTES) return;  // ~9.2 MB scratch
  unsigned short* nhwc = (unsigned short*)d_ws;
  unsigned short* abf2 = (unsigned short*)((char*)d_ws + ABF_OFF);

  k_prep<<<1280, 256, 0, stream>>>(inp, filt, nhwc, abf2);
  k_dcn<<<256, 512, 0, stream>>>(nhwc, abf2, offs, msk, out);
}

// Round 14
// 49.573 us; speedup vs baseline: 1.4890x; 1.0004x over previous
//
#include <hip/hip_runtime.h>
#include <stdint.h>

typedef __attribute__((ext_vector_type(2))) float f32x2;
typedef __attribute__((ext_vector_type(4))) float f32x4;
typedef __attribute__((ext_vector_type(8))) short bf16x8;

static constexpr int N_ = 4, C_ = 256, HW_ = 4096;
static constexpr int CO_ = 256, KTAP = 9;
static constexpr int NSTEP = 72;                 // K-steps of 32
static constexpr int A_PLANE = 16 * 64 * 16;     // one BK=32 plane of A: 16KB

static constexpr size_t NHWC_BYTES = (size_t)N_ * HW_ * C_ * 2;  // 8 MB
static constexpr size_t ABF_OFF    = NHWC_BYTES;
static constexpr size_t ABF_BYTES  = (size_t)NSTEP * A_PLANE;    // 1.18 MB

__device__ inline unsigned f2bf(float f) {
  unsigned u = __builtin_bit_cast(unsigned, f);
  unsigned r = u + 0x7FFFu + ((u >> 16) & 1u);
  return r >> 16;
}
__device__ inline float asf(unsigned u) { return __builtin_bit_cast(float, u); }

// ---------------- merged prep: NCHW->NHWC bf16 + filter->fragment-major ------
__global__ __launch_bounds__(256) void k_prep(const float* __restrict__ in,
                                              const float* __restrict__ filt,
                                              unsigned short* __restrict__ nhwc,
                                              unsigned short* __restrict__ abf2) {
  int b = blockIdx.x;
  int t = threadIdx.x;
  if (b < 1024) {
    __shared__ float tile[64][65];
    int n = b >> 8, cg = (b >> 6) & 3, hwg = b & 63;
    int c0 = cg * 64, hw0 = hwg * 64;
    int col = t & 63, r0 = t >> 6;
#pragma unroll
    for (int i = 0; i < 16; ++i) {
      int row = r0 + i * 4;
      tile[row][col] = in[(size_t)(n * C_ + c0 + row) * HW_ + hw0 + col];
    }
    __syncthreads();
    int pr = t >> 2, cc0 = (t & 3) * 16;
    unsigned us[8];
#pragma unroll
    for (int i = 0; i < 8; ++i) {
      unsigned lo = f2bf(tile[cc0 + 2 * i][pr]);
      unsigned hi = f2bf(tile[cc0 + 2 * i + 1][pr]);
      us[i] = lo | (hi << 16);
    }
    unsigned* dst = (unsigned*)(nhwc + (size_t)(n * HW_ + hw0 + pr) * C_ + c0 + cc0);
    ((uint4*)dst)[0] = make_uint4(us[0], us[1], us[2], us[3]);
    ((uint4*)dst)[1] = make_uint4(us[4], us[5], us[6], us[7]);
  } else {
    // abf2[((s*16 + rb)*64 + lane)*8 + j]: s = tap*8+(c>>5), rb=o>>4,
    // lane = ((c>>3)&3)*16 + (o&15), j = c&7.
    int gid = (b - 1024) * 256 + t;
    int o = gid >> 8, c = gid & 255;
    const float* f = filt + (size_t)(o * C_ + c) * KTAP;
    int rb = o >> 4;
    int lane = ((c >> 3) & 3) * 16 + (o & 15);
    int j = c & 7;
#pragma unroll
    for (int tap = 0; tap < KTAP; ++tap) {
      int s = tap * 8 + (c >> 5);
      abf2[((size_t)(s * 16 + rb) * 64 + lane) * 8 + j] = (unsigned short)f2bf(f[tap]);
    }
  }
}

__device__ __forceinline__ f32x2 unpk(unsigned u) {
  return (f32x2){asf(u << 16), asf(u & 0xffff0000u)};
}

// bilinear combine: 8 channels (one uint4 per corner) -> 16B (8 bf16)
__device__ __forceinline__ uint4 comb8(const uint4& g0, const uint4& g1,
                                       const uint4& g2, const uint4& g3, f32x4 w) {
  f32x2 r0 = w.x * unpk(g0.x) + w.y * unpk(g1.x) + w.z * unpk(g2.x) + w.w * unpk(g3.x);
  f32x2 r1 = w.x * unpk(g0.y) + w.y * unpk(g1.y) + w.z * unpk(g2.y) + w.w * unpk(g3.y);
  f32x2 r2 = w.x * unpk(g0.z) + w.y * unpk(g1.z) + w.z * unpk(g2.z) + w.w * unpk(g3.z);
  f32x2 r3 = w.x * unpk(g0.w) + w.y * unpk(g1.w) + w.z * unpk(g2.w) + w.w * unpk(g3.w);
  unsigned o0, o1, o2, o3;
  asm("v_cvt_pk_bf16_f32 %0, %1, %2" : "=v"(o0) : "v"(r0.x), "v"(r0.y));
  asm("v_cvt_pk_bf16_f32 %0, %1, %2" : "=v"(o1) : "v"(r1.x), "v"(r1.y));
  asm("v_cvt_pk_bf16_f32 %0, %1, %2" : "=v"(o2) : "v"(r2.x), "v"(r2.y));
  asm("v_cvt_pk_bf16_f32 %0, %1, %2" : "=v"(o3) : "v"(r3.x), "v"(r3.y));
  return make_uint4(o0, o1, o2, o3);
}

#define MFMA_BF16 __builtin_amdgcn_mfma_f32_16x16x32_bf16

// One GEMM K-step (S8 = literal 0..7). Consumes aR[S8&3], reloads it with
// A(gs+4) (depth-4 ring; 8%4==0 so the ring is phase-aligned).
#define GSTEP(S8)                                                              \
  do {                                                                         \
    int g4_ = tap * 8 + (S8) + 4;                                              \
    if (g4_ >= NSTEP) g4_ = NSTEP - 1;                                         \
    const char* bb_ = (const char*)&Bl[0][0] + rd + (S8) * 4096;               \
    bf16x8 b0_ = *(const bf16x8*)(bb_ + bo0);                                  \
    bf16x8 b1_ = *(const bf16x8*)(bb_ + bo1);                                  \
    bf16x8 a0_ = aR[(S8) & 3][0];                                              \
    bf16x8 a1_ = aR[(S8) & 3][1];                                              \
    aR[(S8) & 3][0] = *(const bf16x8*)(aoffb + (size_t)g4_ * A_PLANE);         \
    aR[(S8) & 3][1] = *(const bf16x8*)(aoffb + (size_t)g4_ * A_PLANE + 1024);  \
    __builtin_amdgcn_s_setprio(1);                                             \
    acc[0][0] = MFMA_BF16(a0_, b0_, acc[0][0], 0, 0, 0);                       \
    acc[1][0] = MFMA_BF16(a1_, b0_, acc[1][0], 0, 0, 0);                       \
    acc[0][1] = MFMA_BF16(a0_, b1_, acc[0][1], 0, 0, 0);                       \
    acc[1][1] = MFMA_BF16(a1_, b1_, acc[1][1], 0, 0, 0);                       \
    __builtin_amdgcn_s_setprio(0);                                             \
  } while (0)

// ---------------- fused tap-grain kernel: sample tap -> LDS -> GEMM ----------
// 256 blocks (one per output row) x 1024 threads (16 waves, 4/SIMD).
// Waves: (ig 0..7, jg 0..1) -> wave tile 32 Cout x 32 px (acc[2][2]).
// Samplers: thread = (px 0..63, cg 0..15); per tap 8 gather-dwordx4 in two
// 4-load batches (phase start / mid-phase), 2 comb8 + 2 ds_write_b128.
// LDS: 2 tap-buffers x 32KB (8 steps x 4KB); step plane kq=ch>>3 (0..3):
//   addr = kq*1024 + px*16 (bank-minimal b128 read).
__global__ __launch_bounds__(1024, 4) void k_dcn(const unsigned short* __restrict__ nhwc,
                                                 const unsigned short* __restrict__ abf2,
                                                 const float* __restrict__ offs,
                                                 const float* __restrict__ msk,
                                                 float* __restrict__ out) {
  __shared__ __align__(16) unsigned short Bl[2][16384];  // 2 x 32KB tap buffers
  __shared__ float recW[KTAP * 64 * 4];
  __shared__ unsigned recA[KTAP * 64 * 4];

  int bid = blockIdx.x;
  int b = ((bid & 7) << 5) | (bid >> 3);  // XCD-aware swizzle (bijective, 256%8==0)
  int n = b >> 6;
  int ho = b & 63;
  int hw0 = ho << 6;
  int t = threadIdx.x;

  // --- records for all 576 (px, tap) pairs ---
  if (t < 576) {
    int r = t;
    int pl = r / 9;
    int tap = r - pl * 9;
    int hw = hw0 + pl;
    float dy = offs[(size_t)(n * 18 + 2 * tap) * HW_ + hw];
    float dx = offs[(size_t)(n * 18 + 2 * tap + 1) * HW_ + hw];
    float mk = msk[(size_t)(n * 9 + tap) * HW_ + hw];
    float y = (float)(ho - 1 + tap / 3) + dy;
    float x = (float)(pl - 1 + tap % 3) + dx;
    float fy = floorf(y), fx = floorf(x);
    float ly = y - fy, lx = x - fx;
    int y0 = (int)fy, x0 = (int)fx;
    int y1 = y0 + 1, x1 = x0 + 1;
    float vy0 = (y0 >= 0 && y0 < 64) ? 1.f : 0.f;
    float vy1 = (y1 >= 0 && y1 < 64) ? 1.f : 0.f;
    float vx0 = (x0 >= 0 && x0 < 64) ? 1.f : 0.f;
    float vx1 = (x1 >= 0 && x1 < 64) ? 1.f : 0.f;
    int y0c = min(max(y0, 0), 63), y1c = min(max(y1, 0), 63);
    int x0c = min(max(x0, 0), 63), x1c = min(max(x1, 0), 63);
    int base = (tap * 64 + pl) * 4;
    recW[base + 0] = (1.f - ly) * (1.f - lx) * mk * vy0 * vx0;
    recW[base + 1] = (1.f - ly) * lx * mk * vy0 * vx1;
    recW[base + 2] = ly * (1.f - lx) * mk * vy1 * vx0;
    recW[base + 3] = ly * lx * mk * vy1 * vx1;
    recA[base + 0] = (unsigned)((y0c * 64 + x0c) * 512);
    recA[base + 1] = (unsigned)((y0c * 64 + x1c) * 512);
    recA[base + 2] = (unsigned)((y1c * 64 + x0c) * 512);
    recA[base + 3] = (unsigned)((y1c * 64 + x1c) * 512);
  }
  __syncthreads();

  int lane = t & 63, wv = t >> 6;
  int ig = wv >> 1, jg = wv & 1;  // Cout group (32), px group (32)

  // sampler ids
  int px = t >> 4, cg = t & 15;
  unsigned cgo = (unsigned)(cg * 16);
  const char* nb = (const char*)nhwc + (size_t)n * HW_ * C_ * 2;
  const int wchunk = (cg & 3) * 1024 + px * 16;  // plane + px byte
  const int sj0 = (cg >> 2) * 4096;              // step base for batch j=0

  // consumer ids
  const char* aoffb = (const char*)abf2 + ((ig * 2) * 64 + lane) * 16;
  int kq = lane >> 4, pxl = lane & 15;
  const int bo0 = kq * 1024 + (jg * 32 + 0 * 16 + pxl) * 16;
  const int bo1 = kq * 1024 + (jg * 32 + 1 * 16 + pxl) * 16;

  f32x4 acc[2][2];
#pragma unroll
  for (int mi = 0; mi < 2; ++mi)
#pragma unroll
    for (int ni = 0; ni < 2; ++ni) acc[mi][ni] = (f32x4){0.f, 0.f, 0.f, 0.f};

  bf16x8 aR[4][2];

  // ---- prologue: sample tap 0 into buf0; fill A ring (steps 0..3) ----
  {
    f32x4 w0 = *(const f32x4*)&recW[px * 4];
    uint4 ra = *(const uint4*)&recA[px * 4];
    uint4 g0 = *(const uint4*)(nb + ra.x + cgo);
    uint4 g1 = *(const uint4*)(nb + ra.y + cgo);
    uint4 g2 = *(const uint4*)(nb + ra.z + cgo);
    uint4 g3 = *(const uint4*)(nb + ra.w + cgo);
    *(uint4*)((char*)&Bl[0][0] + sj0 + wchunk) = comb8(g0, g1, g2, g3, w0);
    g0 = *(const uint4*)(nb + ra.x + cgo + 256);
    g1 = *(const uint4*)(nb + ra.y + cgo + 256);
    g2 = *(const uint4*)(nb + ra.z + cgo + 256);
    g3 = *(const uint4*)(nb + ra.w + cgo + 256);
    *(uint4*)((char*)&Bl[0][0] + sj0 + 16384 + wchunk) = comb8(g0, g1, g2, g3, w0);
  }
#pragma unroll
  for (int k = 0; k < 4; ++k) {
    aR[k][0] = *(const bf16x8*)(aoffb + (size_t)k * A_PLANE);
    aR[k][1] = *(const bf16x8*)(aoffb + (size_t)k * A_PLANE + 1024);
  }
  __syncthreads();

  // ---- main loop: 9 tap-phases ----
  for (int tap = 0; tap < KTAP; ++tap) {
    const int rd = (tap & 1) << 15;
    const int wr = rd ^ (1 << 15);
    const bool more = tap < KTAP - 1;

    uint4 ga0, ga1, ga2, ga3;
    f32x4 wN;
    uint4 raN;
    if (more) {  // gather batch 0 for tap+1
      wN = *(const f32x4*)&recW[((tap + 1) * 64 + px) * 4];
      raN = *(const uint4*)&recA[((tap + 1) * 64 + px) * 4];
      ga0 = *(const uint4*)(nb + raN.x + cgo);
      ga1 = *(const uint4*)(nb + raN.y + cgo);
      ga2 = *(const uint4*)(nb + raN.z + cgo);
      ga3 = *(const uint4*)(nb + raN.w + cgo);
    }
    __builtin_amdgcn_sched_barrier(0);

    GSTEP(0); GSTEP(1); GSTEP(2); GSTEP(3);

    if (more) {  // write batch 0; issue batch 1
      *(uint4*)((char*)&Bl[0][0] + wr + sj0 + wchunk) = comb8(ga0, ga1, ga2, ga3, wN);
      ga0 = *(const uint4*)(nb + raN.x + cgo + 256);
      ga1 = *(const uint4*)(nb + raN.y + cgo + 256);
      ga2 = *(const uint4*)(nb + raN.z + cgo + 256);
      ga3 = *(const uint4*)(nb + raN.w + cgo + 256);
    }
    __builtin_amdgcn_sched_barrier(0);

    GSTEP(4); GSTEP(5); GSTEP(6); GSTEP(7);

    if (more) {  // write batch 1
      *(uint4*)((char*)&Bl[0][0] + wr + sj0 + 16384 + wchunk) =
          comb8(ga0, ga1, ga2, ga3, wN);
    }
    asm volatile("s_waitcnt lgkmcnt(0)" ::: "memory");
    __builtin_amdgcn_sched_barrier(0);
    __builtin_amdgcn_s_barrier();
    asm volatile("" ::: "memory");
  }

  // ---- epilogue: D col = px, row = Cout ----
  float* ob = out + (size_t)n * CO_ * HW_ + hw0 + jg * 32;
#pragma unroll
  for (int mi = 0; mi < 2; ++mi)
#pragma unroll
    for (int ni = 0; ni < 2; ++ni)
#pragma unroll
      for (int jj = 0; jj < 4; ++jj) {
        int o = ig * 32 + mi * 16 + kq * 4 + jj;
        int hw = ni * 16 + pxl;
        ob[(size_t)o * HW_ + hw] = acc[mi][ni][jj];
      }
}

extern "C" void kernel_launch(void* const* d_in, const int* in_sizes, int n_in,
                              void* d_out, int out_size, void* d_ws, size_t ws_size,
                              hipStream_t stream) {
  const float* inp  = (const float*)d_in[0];
  const float* filt = (const float*)d_in[1];
  const float* offs = (const float*)d_in[2];
  const float* msk  = (const float*)d_in[3];
  float* out = (float*)d_out;
  if (ws_size < ABF_OFF + ABF_BYTES) return;  // ~9.2 MB scratch
  unsigned short* nhwc = (unsigned short*)d_ws;
  unsigned short* abf2 = (unsigned short*)((char*)d_ws + ABF_OFF);

  k_prep<<<1280, 256, 0, stream>>>(inp, filt, nhwc, abf2);
  k_dcn<<<256, 1024, 0, stream>>>(nhwc, abf2, offs, msk, out);
}

// Round 15
// 45.847 us; speedup vs baseline: 1.6100x; 1.0813x over previous
//
#include <hip/hip_runtime.h>
#include <stdint.h>

typedef __attribute__((ext_vector_type(2))) float f32x2;
typedef __attribute__((ext_vector_type(4))) float f32x4;
typedef __attribute__((ext_vector_type(8))) short bf16x8;

static constexpr int N_ = 4, C_ = 256, HW_ = 4096;
static constexpr int CO_ = 256, KTAP = 9;
static constexpr int NSTEP = 72;                 // K-steps of 32
static constexpr int A_PLANE = 16 * 64 * 16;     // one BK=32 plane of A: 16KB

static constexpr size_t NHWC_BYTES = (size_t)N_ * HW_ * C_ * 2;  // 8 MB
static constexpr size_t ABF_OFF    = NHWC_BYTES;
static constexpr size_t ABF_BYTES  = (size_t)NSTEP * A_PLANE;    // 1.18 MB

__device__ inline unsigned f2bf(float f) {
  unsigned u = __builtin_bit_cast(unsigned, f);
  unsigned r = u + 0x7FFFu + ((u >> 16) & 1u);
  return r >> 16;
}
__device__ inline float asf(unsigned u) { return __builtin_bit_cast(float, u); }

// ---------------- merged prep: NCHW->NHWC bf16 + filter->fragment-major ------
__global__ __launch_bounds__(256) void k_prep(const float* __restrict__ in,
                                              const float* __restrict__ filt,
                                              unsigned short* __restrict__ nhwc,
                                              unsigned short* __restrict__ abf2) {
  int b = blockIdx.x;
  int t = threadIdx.x;
  if (b < 1024) {
    __shared__ float tile[64][65];
    int n = b >> 8, cg = (b >> 6) & 3, hwg = b & 63;
    int c0 = cg * 64, hw0 = hwg * 64;
    int col = t & 63, r0 = t >> 6;
#pragma unroll
    for (int i = 0; i < 16; ++i) {
      int row = r0 + i * 4;
      tile[row][col] = in[(size_t)(n * C_ + c0 + row) * HW_ + hw0 + col];
    }
    __syncthreads();
    int pr = t >> 2, cc0 = (t & 3) * 16;
    unsigned us[8];
#pragma unroll
    for (int i = 0; i < 8; ++i) {
      unsigned lo = f2bf(tile[cc0 + 2 * i][pr]);
      unsigned hi = f2bf(tile[cc0 + 2 * i + 1][pr]);
      us[i] = lo | (hi << 16);
    }
    unsigned* dst = (unsigned*)(nhwc + (size_t)(n * HW_ + hw0 + pr) * C_ + c0 + cc0);
    ((uint4*)dst)[0] = make_uint4(us[0], us[1], us[2], us[3]);
    ((uint4*)dst)[1] = make_uint4(us[4], us[5], us[6], us[7]);
  } else {
    // abf2[((s*16 + rb)*64 + lane)*8 + j]: s = tap*8+(c>>5), rb=o>>4,
    // lane = ((c>>3)&3)*16 + (o&15), j = c&7.
    int gid = (b - 1024) * 256 + t;
    int o = gid >> 8, c = gid & 255;
    const float* f = filt + (size_t)(o * C_ + c) * KTAP;
    int rb = o >> 4;
    int lane = ((c >> 3) & 3) * 16 + (o & 15);
    int j = c & 7;
#pragma unroll
    for (int tap = 0; tap < KTAP; ++tap) {
      int s = tap * 8 + (c >> 5);
      abf2[((size_t)(s * 16 + rb) * 64 + lane) * 8 + j] = (unsigned short)f2bf(f[tap]);
    }
  }
}

__device__ __forceinline__ f32x2 unpk(unsigned u) {
  return (f32x2){asf(u << 16), asf(u & 0xffff0000u)};
}

// bilinear combine: 8 channels (one uint4 per corner) -> 16B (8 bf16)
__device__ __forceinline__ uint4 comb8(const uint4& g0, const uint4& g1,
                                       const uint4& g2, const uint4& g3, f32x4 w) {
  f32x2 r0 = w.x * unpk(g0.x) + w.y * unpk(g1.x) + w.z * unpk(g2.x) + w.w * unpk(g3.x);
  f32x2 r1 = w.x * unpk(g0.y) + w.y * unpk(g1.y) + w.z * unpk(g2.y) + w.w * unpk(g3.y);
  f32x2 r2 = w.x * unpk(g0.z) + w.y * unpk(g1.z) + w.z * unpk(g2.z) + w.w * unpk(g3.z);
  f32x2 r3 = w.x * unpk(g0.w) + w.y * unpk(g1.w) + w.z * unpk(g2.w) + w.w * unpk(g3.w);
  unsigned o0, o1, o2, o3;
  asm("v_cvt_pk_bf16_f32 %0, %1, %2" : "=v"(o0) : "v"(r0.x), "v"(r0.y));
  asm("v_cvt_pk_bf16_f32 %0, %1, %2" : "=v"(o1) : "v"(r1.x), "v"(r1.y));
  asm("v_cvt_pk_bf16_f32 %0, %1, %2" : "=v"(o2) : "v"(r2.x), "v"(r2.y));
  asm("v_cvt_pk_bf16_f32 %0, %1, %2" : "=v"(o3) : "v"(r3.x), "v"(r3.y));
  return make_uint4(o0, o1, o2, o3);
}

#define MFMA_BF16 __builtin_amdgcn_mfma_f32_16x16x32_bf16

// One consumer K-step (S8 literal 0..7). Consumes aR[S8&3], reloads with
// A(gs+4) (depth-4 ring; phase length 8 is a multiple of 4).
#define GSTEP(S8)                                                              \
  do {                                                                         \
    int g4_ = tap * 8 + (S8) + 4;                                              \
    if (g4_ >= NSTEP) g4_ = NSTEP - 1;                                         \
    const char* bb_ = (const char*)&Bl[0][0] + rd + (S8) * 4096;               \
    bf16x8 b0_ = *(const bf16x8*)(bb_ + bo0);                                  \
    bf16x8 b1_ = *(const bf16x8*)(bb_ + bo1);                                  \
    bf16x8 b2_ = *(const bf16x8*)(bb_ + bo2);                                  \
    bf16x8 b3_ = *(const bf16x8*)(bb_ + bo3);                                  \
    bf16x8 a0_ = aR[(S8) & 3][0];                                              \
    bf16x8 a1_ = aR[(S8) & 3][1];                                              \
    aR[(S8) & 3][0] = *(const bf16x8*)(aoffb + (size_t)g4_ * A_PLANE);         \
    aR[(S8) & 3][1] = *(const bf16x8*)(aoffb + (size_t)g4_ * A_PLANE + 1024);  \
    __builtin_amdgcn_s_setprio(1);                                             \
    acc[0][0] = MFMA_BF16(a0_, b0_, acc[0][0], 0, 0, 0);                       \
    acc[1][0] = MFMA_BF16(a1_, b0_, acc[1][0], 0, 0, 0);                       \
    acc[0][1] = MFMA_BF16(a0_, b1_, acc[0][1], 0, 0, 0);                       \
    acc[1][1] = MFMA_BF16(a1_, b1_, acc[1][1], 0, 0, 0);                       \
    acc[0][2] = MFMA_BF16(a0_, b2_, acc[0][2], 0, 0, 0);                       \
    acc[1][2] = MFMA_BF16(a1_, b2_, acc[1][2], 0, 0, 0);                       \
    acc[0][3] = MFMA_BF16(a0_, b3_, acc[0][3], 0, 0, 0);                       \
    acc[1][3] = MFMA_BF16(a1_, b3_, acc[1][3], 0, 0, 0);                       \
    __builtin_amdgcn_s_setprio(0);                                             \
  } while (0)

// ------- producer/consumer tap-grain kernel: sample tap -> LDS -> GEMM -------
// 256 blocks (one per output row) x 1024 threads (16 waves, 4/SIMD):
//   waves 0-7  = consumers: wave tile 32 Cout x 64 px, 8 barrier-free steps/tap
//   waves 8-15 = producers: 512 thr = (px 0..63, cq 0..7), 32 ch each/tap
// LDS: 2 tap-buffers x 32KB (8 steps x 4KB); step plane kq=ch>>3 mod 4:
//   addr = kq*1024 + px*16 (bank-minimal b128 read AND write).
// One raw s_barrier per tap; producers-only lgkm drain; consumer A-ring loads
// stay in flight across the barrier.
__global__ __launch_bounds__(1024, 4) void k_dcn(const unsigned short* __restrict__ nhwc,
                                                 const unsigned short* __restrict__ abf2,
                                                 const float* __restrict__ offs,
                                                 const float* __restrict__ msk,
                                                 float* __restrict__ out) {
  __shared__ __align__(16) unsigned short Bl[2][16384];  // 2 x 32KB tap buffers
  __shared__ float recW[KTAP * 64 * 4];
  __shared__ unsigned recA[KTAP * 64 * 4];

  int bid = blockIdx.x;
  int b = ((bid & 7) << 5) | (bid >> 3);  // XCD-aware swizzle (bijective, 256%8==0)
  int n = b >> 6;
  int ho = b & 63;
  int hw0 = ho << 6;
  int t = threadIdx.x;

  // --- records for all 576 (px, tap) pairs ---
  if (t < 576) {
    int r = t;
    int pl = r / 9;
    int tap = r - pl * 9;
    int hw = hw0 + pl;
    float dy = offs[(size_t)(n * 18 + 2 * tap) * HW_ + hw];
    float dx = offs[(size_t)(n * 18 + 2 * tap + 1) * HW_ + hw];
    float mk = msk[(size_t)(n * 9 + tap) * HW_ + hw];
    float y = (float)(ho - 1 + tap / 3) + dy;
    float x = (float)(pl - 1 + tap % 3) + dx;
    float fy = floorf(y), fx = floorf(x);
    float ly = y - fy, lx = x - fx;
    int y0 = (int)fy, x0 = (int)fx;
    int y1 = y0 + 1, x1 = x0 + 1;
    float vy0 = (y0 >= 0 && y0 < 64) ? 1.f : 0.f;
    float vy1 = (y1 >= 0 && y1 < 64) ? 1.f : 0.f;
    float vx0 = (x0 >= 0 && x0 < 64) ? 1.f : 0.f;
    float vx1 = (x1 >= 0 && x1 < 64) ? 1.f : 0.f;
    int y0c = min(max(y0, 0), 63), y1c = min(max(y1, 0), 63);
    int x0c = min(max(x0, 0), 63), x1c = min(max(x1, 0), 63);
    int base = (tap * 64 + pl) * 4;
    recW[base + 0] = (1.f - ly) * (1.f - lx) * mk * vy0 * vx0;
    recW[base + 1] = (1.f - ly) * lx * mk * vy0 * vx1;
    recW[base + 2] = ly * (1.f - lx) * mk * vy1 * vx0;
    recW[base + 3] = ly * lx * mk * vy1 * vx1;
    recA[base + 0] = (unsigned)((y0c * 64 + x0c) * 512);
    recA[base + 1] = (unsigned)((y0c * 64 + x1c) * 512);
    recA[base + 2] = (unsigned)((y1c * 64 + x0c) * 512);
    recA[base + 3] = (unsigned)((y1c * 64 + x1c) * 512);
  }
  __syncthreads();

  int lane = t & 63, wv = t >> 6;
  bool cons = wv < 8;

  if (cons) {
    // =================== consumer: pure GEMM ===================
    const char* aoffb = (const char*)abf2 + ((wv * 2) * 64 + lane) * 16;
    int kq = lane >> 4, pxl = lane & 15;
    const int bo0 = kq * 1024 + (0 * 16 + pxl) * 16;
    const int bo1 = kq * 1024 + (1 * 16 + pxl) * 16;
    const int bo2 = kq * 1024 + (2 * 16 + pxl) * 16;
    const int bo3 = kq * 1024 + (3 * 16 + pxl) * 16;

    f32x4 acc[2][4];
#pragma unroll
    for (int mi = 0; mi < 2; ++mi)
#pragma unroll
      for (int ni = 0; ni < 4; ++ni) acc[mi][ni] = (f32x4){0.f, 0.f, 0.f, 0.f};

    bf16x8 aR[4][2];
#pragma unroll
    for (int k = 0; k < 4; ++k) {
      aR[k][0] = *(const bf16x8*)(aoffb + (size_t)k * A_PLANE);
      aR[k][1] = *(const bf16x8*)(aoffb + (size_t)k * A_PLANE + 1024);
    }
    asm volatile("" ::: "memory");
    __builtin_amdgcn_s_barrier();  // pairs with producers' prologue
    asm volatile("" ::: "memory");

    for (int tap = 0; tap < KTAP; ++tap) {
      const int rd = (tap & 1) << 15;
      GSTEP(0); GSTEP(1); GSTEP(2); GSTEP(3);
      GSTEP(4); GSTEP(5); GSTEP(6); GSTEP(7);
      asm volatile("" ::: "memory");
      __builtin_amdgcn_s_barrier();
      asm volatile("" ::: "memory");
    }

    // epilogue: D col = px, row = Cout
    float* ob = out + (size_t)n * CO_ * HW_ + hw0;
#pragma unroll
    for (int mi = 0; mi < 2; ++mi)
#pragma unroll
      for (int ni = 0; ni < 4; ++ni)
#pragma unroll
        for (int jj = 0; jj < 4; ++jj) {
          int o = wv * 32 + mi * 16 + kq * 4 + jj;
          int hw = ni * 16 + pxl;
          ob[(size_t)o * HW_ + hw] = acc[mi][ni][jj];
        }
  } else {
    // =================== producer: pure sampler ===================
    int p = t - 512;
    int px = p >> 3, cq = p & 7;
    unsigned cq16 = (unsigned)(cq * 16);
    const char* nb = (const char*)nhwc + (size_t)n * HW_ * C_ * 2;
    const int wchunk = (cq & 3) * 1024 + px * 16;  // plane + px byte
    const int sj0 = (cq >> 2) * 4096;              // step base for batch j=0

    // prologue: sample tap 0 into buf0
    {
      f32x4 w0 = *(const f32x4*)&recW[px * 4];
      uint4 ra = *(const uint4*)&recA[px * 4];
      uint4 g0[4], g1[4], g2[4], g3[4];
#pragma unroll
      for (int j = 0; j < 4; ++j) {
        unsigned o_ = (unsigned)(j * 128) + cq16;
        g0[j] = *(const uint4*)(nb + ra.x + o_);
        g1[j] = *(const uint4*)(nb + ra.y + o_);
        g2[j] = *(const uint4*)(nb + ra.z + o_);
        g3[j] = *(const uint4*)(nb + ra.w + o_);
      }
      char* wb = (char*)&Bl[0][0] + sj0 + wchunk;
#pragma unroll
      for (int j = 0; j < 4; ++j)
        *(uint4*)(wb + j * 8192) = comb8(g0[j], g1[j], g2[j], g3[j], w0);
      asm volatile("s_waitcnt lgkmcnt(0)" ::: "memory");
    }
    asm volatile("" ::: "memory");
    __builtin_amdgcn_s_barrier();
    asm volatile("" ::: "memory");

    for (int tap = 0; tap < KTAP; ++tap) {
      const int wr = ((tap & 1) ^ 1) << 15;
      if (tap < KTAP - 1) {
        f32x4 wN = *(const f32x4*)&recW[((tap + 1) * 64 + px) * 4];
        uint4 raN = *(const uint4*)&recA[((tap + 1) * 64 + px) * 4];
        uint4 g0[4], g1[4], g2[4], g3[4];
#pragma unroll
        for (int j = 0; j < 4; ++j) {
          unsigned o_ = (unsigned)(j * 128) + cq16;
          g0[j] = *(const uint4*)(nb + raN.x + o_);
          g1[j] = *(const uint4*)(nb + raN.y + o_);
          g2[j] = *(const uint4*)(nb + raN.z + o_);
          g3[j] = *(const uint4*)(nb + raN.w + o_);
        }
        char* wb = (char*)&Bl[0][0] + wr + sj0 + wchunk;
#pragma unroll
        for (int j = 0; j < 4; ++j)
          *(uint4*)(wb + j * 8192) = comb8(g0[j], g1[j], g2[j], g3[j], wN);
        asm volatile("s_waitcnt lgkmcnt(0)" ::: "memory");
      }
      asm volatile("" ::: "memory");
      __builtin_amdgcn_s_barrier();
      asm volatile("" ::: "memory");
    }
  }
}

extern "C" void kernel_launch(void* const* d_in, const int* in_sizes, int n_in,
                              void* d_out, int out_size, void* d_ws, size_t ws_size,
                              hipStream_t stream) {
  const float* inp  = (const float*)d_in[0];
  const float* filt = (const float*)d_in[1];
  const float* offs = (const float*)d_in[2];
  const float* msk  = (const float*)d_in[3];
  float* out = (float*)d_out;
  if (ws_size < ABF_OFF + ABF_BYTES) return;  // ~9.2 MB scratch
  unsigned short* nhwc = (unsigned short*)d_ws;
  unsigned short* abf2 = (unsigned short*)((char*)d_ws + ABF_OFF);

  k_prep<<<1280, 256, 0, stream>>>(inp, filt, nhwc, abf2);
  k_dcn<<<256, 1024, 0, stream>>>(nhwc, abf2, offs, msk, out);
}